// Round 7
// baseline (420.113 us; speedup 1.0000x reference)
//
#include <hip/hip_runtime.h>
#include <hip/hip_bf16.h>
#include <math.h>

#define S 2048
#define DM 2048
#define NH 16
#define DH 128
#define DR 64
#define DKV 512
#define DQ 1024
#define DQK 192  // DH + DR

typedef __bf16 bf16x8 __attribute__((ext_vector_type(8)));
typedef float f32x4 __attribute__((ext_vector_type(4)));
typedef unsigned short u16;

__device__ inline unsigned int pack2_bf16(float a, float b) {
    __hip_bfloat16 ha = __float2bfloat16(a);
    __hip_bfloat16 hb = __float2bfloat16(b);
    unsigned short ua = *reinterpret_cast<unsigned short*>(&ha);
    unsigned short ub = *reinterpret_cast<unsigned short*>(&hb);
    return (unsigned int)ua | ((unsigned int)ub << 16);
}
__device__ inline u16 f2bf(float v) {
    __hip_bfloat16 hb = __float2bfloat16(v);
    return *reinterpret_cast<u16*>(&hb);
}
__device__ inline float bf2f(u16 b) {
    return __bfloat162float(*reinterpret_cast<const __hip_bfloat16*>(&b));
}
__device__ inline void gload_lds16(const void* g, void* l) {
    __builtin_amdgcn_global_load_lds(
        (const __attribute__((address_space(1))) void*)g,
        (__attribute__((address_space(3))) void*)l, 16, 0, 0);
}
__device__ inline void store_out(float* p, float v) { *p = v; }
__device__ inline void store_out(u16* p, float v) { *p = f2bf(v); }

// ---------------- RoPE cos/sin table ----------------
__global__ void rope_table_kernel(float* __restrict__ cosT, float* __restrict__ sinT) {
    int idx = blockIdx.x * blockDim.x + threadIdx.x;
    if (idx >= S * (DR / 2)) return;
    int pos = idx / (DR / 2);
    int j   = idx % (DR / 2);
    float inv = __expf(-((float)(2 * j) / (float)DR) * logf(10000.0f));
    float ang = (float)pos * inv;
    cosT[idx] = cosf(ang);
    sinT[idx] = sinf(ang);
}

// ---------------- f32 -> bf16 elementwise (x) ----------------
__global__ void convert_bf16_kernel(const float* __restrict__ in, u16* __restrict__ outp, int n4) {
    int idx = blockIdx.x * blockDim.x + threadIdx.x;
    if (idx >= n4) return;
    float4 v = *reinterpret_cast<const float4*>(&in[(size_t)idx * 4]);
    uint2 w;
    w.x = pack2_bf16(v.x, v.y);
    w.y = pack2_bf16(v.z, v.w);
    *reinterpret_cast<uint2*>(&outp[(size_t)idx * 4]) = w;
}

// ---------------- transpose-convert: W f32 [K][N] -> WT bf16 [N][K] ----------------
__global__ __launch_bounds__(256) void wt_convert_kernel(const float* __restrict__ W,
                                                         u16* __restrict__ WT, int K, int N) {
    __shared__ u16 tile[64][65];
    const int n0 = blockIdx.x * 64;
    const int k0 = blockIdx.y * 64;
    const int tx = threadIdx.x & 15;
    const int ty = threadIdx.x >> 4;
#pragma unroll
    for (int rep = 0; rep < 4; ++rep) {
        int kk = rep * 16 + ty;
        float4 v = *reinterpret_cast<const float4*>(&W[(size_t)(k0 + kk) * N + n0 + tx * 4]);
        tile[kk][tx * 4 + 0] = f2bf(v.x);
        tile[kk][tx * 4 + 1] = f2bf(v.y);
        tile[kk][tx * 4 + 2] = f2bf(v.z);
        tile[kk][tx * 4 + 3] = f2bf(v.w);
    }
    __syncthreads();
#pragma unroll
    for (int rep = 0; rep < 4; ++rep) {
        int nn = rep * 16 + ty;
        uint2 w;
        w.x = (unsigned int)tile[tx * 4 + 0][nn] | ((unsigned int)tile[tx * 4 + 1][nn] << 16);
        w.y = (unsigned int)tile[tx * 4 + 2][nn] | ((unsigned int)tile[tx * 4 + 3][nn] << 16);
        *reinterpret_cast<uint2*>(&WT[(size_t)(n0 + nn) * K + k0 + tx * 4]) = w;
    }
}

// ---------------- bf16 MFMA GEMM: C = A[M,K] @ BT[N,K]^T (R6 structure, conflict-free maps) ----------------
template <typename OutT>
__global__ __launch_bounds__(256) void gemm_bf16_kernel(
    const u16* __restrict__ A, const u16* __restrict__ BT,
    OutT* __restrict__ C0, OutT* __restrict__ C1, OutT* __restrict__ C2,
    int n1, int n2, int ld0, int ld1, int ld2, int K) {
    __shared__ u16 lds[2][6144];
    const int tid  = threadIdx.x;
    const int wave = tid >> 6;
    const int lane = tid & 63;
    const int c16  = lane & 15;
    const int g    = lane >> 4;
    const int bm = blockIdx.y * 64;
    const int bn = blockIdx.x * 128;
    const int wm = (wave >> 1) * 32;
    const int wn = (wave & 1) * 64;

    f32x4 acc[2][4];
#pragma unroll
    for (int i = 0; i < 2; ++i)
#pragma unroll
        for (int j = 0; j < 4; ++j) acc[i][j] = f32x4{0.f, 0.f, 0.f, 0.f};

    auto stage = [&](int buf, int k0) {
        {
            int L = tid;
            int rp = L >> 3, e = L & 7, x = e ^ (rp & 7);
            int row = 2 * rp + (x >> 2), kc = x & 3;
            gload_lds16(A + (size_t)(bm + row) * K + k0 + kc * 8, &lds[buf][wave * 512]);
        }
#pragma unroll
        for (int r = 0; r < 2; ++r) {
            int L = r * 256 + tid;
            int rp = L >> 3, e = L & 7, x = e ^ (rp & 7);
            int row = 2 * rp + (x >> 2), kc = x & 3;
            gload_lds16(BT + (size_t)(bn + row) * K + k0 + kc * 8,
                        &lds[buf][2048 + (r * 256 + wave * 64) * 8]);
        }
    };

    const int NT = K / 32;
    stage(0, 0);
    __syncthreads();
    int cur = 0;
    for (int t = 0; t < NT; ++t) {
        if (t + 1 < NT) stage(cur ^ 1, (t + 1) * 32);
        bf16x8 af[2], bfr[4];
#pragma unroll
        for (int i = 0; i < 2; ++i) {
            int row  = wm + i * 16 + c16;
            int slot = ((row >> 1) << 3) + ((((row & 1) << 2) + g) ^ ((row >> 1) & 7));
            af[i] = *reinterpret_cast<const bf16x8*>(&lds[cur][slot * 8]);
        }
#pragma unroll
        for (int j = 0; j < 4; ++j) {
            int row  = wn + j * 16 + c16;
            int slot = ((row >> 1) << 3) + ((((row & 1) << 2) + g) ^ ((row >> 1) & 7));
            bfr[j] = *reinterpret_cast<const bf16x8*>(&lds[cur][2048 + slot * 8]);
        }
#pragma unroll
        for (int i = 0; i < 2; ++i)
#pragma unroll
            for (int j = 0; j < 4; ++j)
                acc[i][j] = __builtin_amdgcn_mfma_f32_16x16x32_bf16(af[i], bfr[j], acc[i][j], 0, 0, 0);
        __syncthreads();
        cur ^= 1;
    }

    OutT* Cp; int ss, ld;
    if (bn < n1)      { Cp = C0; ss = 0;  ld = ld0; }
    else if (bn < n2) { Cp = C1; ss = n1; ld = ld1; }
    else              { Cp = C2; ss = n2; ld = ld2; }
#pragma unroll
    for (int i = 0; i < 2; ++i)
#pragma unroll
        for (int j = 0; j < 4; ++j) {
            int mrow = bm + wm + i * 16 + g * 4;
            size_t base = (size_t)mrow * ld + (bn - ss) + wn + j * 16 + c16;
#pragma unroll
            for (int r = 0; r < 4; ++r) store_out(&Cp[base + (size_t)r * ld], acc[i][j][r]);
        }
}

// ---------------- assemble q/k -> bf16 (NH, S, 192), RoPE on last 64, optional scale ----------------
__global__ void assemble_qk_bf16_kernel(const u16* __restrict__ c_raw,
                                        const u16* __restrict__ r_raw,
                                        const float* __restrict__ cosT,
                                        const float* __restrict__ sinT,
                                        u16* __restrict__ outp,
                                        float scale, int total) {
    int idx = blockIdx.x * blockDim.x + threadIdx.x;
    if (idx >= total) return;
    int d    = idx % DQK;
    int rest = idx / DQK;
    int pos  = rest % S;
    int h    = rest / S;
    float val;
    if (d < DH) {
        val = bf2f(c_raw[(size_t)pos * (NH * DH) + h * DH + d]);
    } else {
        int r = d - DH;
        int j = r >> 1;
        float t1 = bf2f(r_raw[(size_t)pos * (NH * DR) + h * DR + 2 * j]);
        float t2 = bf2f(r_raw[(size_t)pos * (NH * DR) + h * DR + 2 * j + 1]);
        float c  = cosT[pos * (DR / 2) + j];
        float s  = sinT[pos * (DR / 2) + j];
        val = (r & 1) ? (t1 * s + t2 * c) : (t1 * c - t2 * s);
    }
    outp[idx] = f2bf(val * scale);
}

// ---------------- V transpose: (s, NH*DH) bf16 -> (NH, DH, S) bf16 ----------------
__global__ __launch_bounds__(256) void v_transpose_bf16_kernel(const u16* __restrict__ v_bf,
                                                               u16* __restrict__ vt) {
    __shared__ u16 tile[64][65];
    const int j0 = blockIdx.x * 64;
    const int d0 = blockIdx.y * 64;
    const int h  = blockIdx.z;
    const int tx = threadIdx.x & 15;
    const int ty = threadIdx.x >> 4;
#pragma unroll
    for (int rep = 0; rep < 4; ++rep) {
        int j = rep * 16 + ty;
        ushort4 v = *reinterpret_cast<const ushort4*>(
            &v_bf[(size_t)(j0 + j) * (NH * DH) + h * DH + d0 + tx * 4]);
        tile[j][tx * 4 + 0] = v.x;
        tile[j][tx * 4 + 1] = v.y;
        tile[j][tx * 4 + 2] = v.z;
        tile[j][tx * 4 + 3] = v.w;
    }
    __syncthreads();
#pragma unroll
    for (int rep = 0; rep < 4; ++rep) {
        int d = rep * 16 + ty;
        uint2 w;
        w.x = (unsigned int)tile[tx * 4 + 0][d] | ((unsigned int)tile[tx * 4 + 1][d] << 16);
        w.y = (unsigned int)tile[tx * 4 + 2][d] | ((unsigned int)tile[tx * 4 + 3][d] << 16);
        *reinterpret_cast<uint2*>(&vt[((size_t)h * DH + d0 + d) * S + j0 + tx * 4]) = w;
    }
}

// ---------------- MFMA flash attention v5: 1-wave blocks, direct-from-L2 K/V, no barriers ----------------
// XCD head-pinning (L2-resident K/V), per-wave causal range kend=qw+16, defer-max,
// wave-private conflict-free P LDS. No __syncthreads anywhere.
__global__ __launch_bounds__(64) void attn_mfma_kernel(const u16* __restrict__ q,   // (NH,S,192) pre-scaled
                                                       const u16* __restrict__ k,   // (NH,S,192)
                                                       const u16* __restrict__ vt,  // (NH,DH,S)
                                                       u16* __restrict__ outp) {    // (S, NH*DH) bf16
    const int wgid = blockIdx.x;
    const int xcd  = wgid & 7;
    const int i    = wgid >> 3;        // 0..255 per XCD (2 heads x 128 q-tiles)
    const int j    = i >> 1;
    const int h    = xcd * 2 + (i & 1);
    const int qt   = (i & 1) ? j : (127 - j);  // interleave big/small for CU balance
    const int qw   = qt * 16;

    const int lane = threadIdx.x;
    const int col  = lane & 15;
    const int g    = lane >> 4;

    __shared__ __align__(16) u16 p_lds[512];   // wave-private P tile
    const int pv7 = (col >> 1) & 7;
    const int pvb = (col & 1) << 2;

    // Q fragments: lane holds Q[qw+col][g*8+e + 32c]
    bf16x8 qf[6];
    const u16* qbase = q + ((size_t)h * S + qw + col) * DQK + g * 8;
#pragma unroll
    for (int c = 0; c < 6; ++c) qf[c] = *reinterpret_cast<const bf16x8*>(qbase + c * 32);

    f32x4 acc[8];
#pragma unroll
    for (int c = 0; c < 8; ++c) acc[c] = f32x4{0.f, 0.f, 0.f, 0.f};
    float m_run = -1e30f, l_run = 0.f;

    const int kend = qw + 16;
    for (int j0 = 0; j0 < kend; j0 += 32) {
        const bool do_t1 = (j0 + 16) < kend;
        // ---- QK^T: K fragments straight from global (L2-resident)
        f32x4 st[2];
        st[0] = f32x4{0.f, 0.f, 0.f, 0.f};
        st[1] = f32x4{0.f, 0.f, 0.f, 0.f};
        const u16* kbase = k + ((size_t)h * S + j0 + col) * DQK + g * 8;
#pragma unroll
        for (int c = 0; c < 6; ++c) {
            bf16x8 kf = *reinterpret_cast<const bf16x8*>(kbase + c * 32);
            st[0] = __builtin_amdgcn_mfma_f32_16x16x32_bf16(kf, qf[c], st[0], 0, 0, 0);
        }
        if (do_t1) {
            const u16* kbase1 = kbase + (size_t)16 * DQK;
#pragma unroll
            for (int c = 0; c < 6; ++c) {
                bf16x8 kf = *reinterpret_cast<const bf16x8*>(kbase1 + c * 32);
                st[1] = __builtin_amdgcn_mfma_f32_16x16x32_bf16(kf, qf[c], st[1], 0, 0, 0);
            }
        } else {
            st[1] = f32x4{-1e30f, -1e30f, -1e30f, -1e30f};
        }
        // ---- causal mask (q = qw+col, key = j0+16t+4g+r)
#pragma unroll
        for (int t = 0; t < 2; ++t) {
            if (j0 + 16 * t + 15 > qw) {
#pragma unroll
                for (int r = 0; r < 4; ++r) {
                    int key = j0 + 16 * t + 4 * g + r;
                    st[t][r] = (key > qw + col) ? -1e30f : st[t][r];
                }
            }
        }
        // ---- online softmax with defer-max
        float tmax = fmaxf(fmaxf(fmaxf(st[0][0], st[0][1]), fmaxf(st[0][2], st[0][3])),
                           fmaxf(fmaxf(st[1][0], st[1][1]), fmaxf(st[1][2], st[1][3])));
        tmax = fmaxf(tmax, __shfl_xor(tmax, 16));
        tmax = fmaxf(tmax, __shfl_xor(tmax, 32));
        float m_new;
        if (__all(tmax - m_run <= 8.0f)) {
            m_new = m_run;
        } else {
            m_new = fmaxf(m_run, tmax);
            float r_scale = __expf(m_run - m_new);
            l_run *= r_scale;
#pragma unroll
            for (int c = 0; c < 8; ++c) {
                acc[c][0] *= r_scale; acc[c][1] *= r_scale;
                acc[c][2] *= r_scale; acc[c][3] *= r_scale;
            }
            m_run = m_new;
        }
        float p[8];
        float psum = 0.f;
#pragma unroll
        for (int t = 0; t < 2; ++t)
#pragma unroll
            for (int r = 0; r < 4; ++r) {
                float pv = __expf(st[t][r] - m_new);
                p[t * 4 + r] = pv;
                psum += pv;
            }
        psum += __shfl_xor(psum, 16);
        psum += __shfl_xor(psum, 32);
        l_run += psum;
        // ---- P -> p_lds (wave-private; lgkmcnt ordering only)
#pragma unroll
        for (int t = 0; t < 2; ++t) {
            uint2 w;
            w.x = pack2_bf16(p[t * 4 + 0], p[t * 4 + 1]);
            w.y = pack2_bf16(p[t * 4 + 2], p[t * 4 + 3]);
            int ch   = 2 * t + (g >> 1);
            int slot = ((col >> 1) << 3) + ((pvb + ch) ^ pv7);
            *reinterpret_cast<uint2*>(&p_lds[slot * 8 + (g & 1) * 4]) = w;
        }
        {
            int slot = ((col >> 1) << 3) + ((pvb + g) ^ pv7);
            bf16x8 pf = *reinterpret_cast<const bf16x8*>(&p_lds[slot * 8]);
            // ---- PV: V^T fragments straight from global (L2-resident)
            const u16* vb = vt + ((size_t)h * DH + col) * S + j0 + g * 8;
#pragma unroll
            for (int c = 0; c < 8; ++c) {
                bf16x8 vf = *reinterpret_cast<const bf16x8*>(vb + (size_t)c * 16 * S);
                acc[c] = __builtin_amdgcn_mfma_f32_16x16x32_bf16(vf, pf, acc[c], 0, 0, 0);
            }
        }
    }

    float inv_l = 1.0f / l_run;
#pragma unroll
    for (int c = 0; c < 8; ++c)
#pragma unroll
        for (int r = 0; r < 4; ++r)
            outp[(size_t)(qw + col) * (NH * DH) + h * DH + 16 * c + 4 * g + r] = f2bf(acc[c][r] * inv_l);
}

// ---------------- launch ----------------
extern "C" void kernel_launch(void* const* d_in, const int* in_sizes, int n_in,
                              void* d_out, int out_size, void* d_ws, size_t ws_size,
                              hipStream_t stream) {
    const float* x         = (const float*)d_in[0];
    const float* W_kv_down = (const float*)d_in[2];
    const float* W_k_up    = (const float*)d_in[3];
    const float* W_v_up    = (const float*)d_in[4];
    const float* W_q_down  = (const float*)d_in[5];
    const float* W_q_up    = (const float*)d_in[6];
    const float* W_q_rope  = (const float*)d_in[7];
    const float* W_k_rope  = (const float*)d_in[8];
    const float* W_out     = (const float*)d_in[9];
    float* out = (float*)d_out;

    float* w = (float*)d_ws;
    float* cosT = w;
    float* sinT = w + (size_t)S * (DR / 2);
    u16* b = (u16*)(w + 2 * (size_t)S * (DR / 2));
    size_t off = 0;
    u16* x_bf    = b + off; off += (size_t)S * DM;
    u16* WT1     = b + off; off += (size_t)2560 * DM;
    u16* WT2     = b + off; off += (size_t)4096 * DKV;
    u16* WT3     = b + off; off += (size_t)3072 * DQ;
    u16* WT4     = b + off; off += (size_t)DM * DM;
    u16* down_kv = b + off; off += (size_t)S * DKV;
    u16* down_q  = b + off; off += (size_t)S * DQ;
    u16* kr_bf   = b + off; off += (size_t)S * NH * DR;
    u16* kc_bf   = b + off; off += (size_t)S * NH * DH;
    u16* v_bf    = b + off; off += (size_t)S * NH * DH;
    u16* qc_bf   = b + off; off += (size_t)S * NH * DH;
    u16* qr_bf   = b + off; off += (size_t)S * NH * DR;
    u16* q_asm   = b + off; off += (size_t)NH * S * DQK;
    u16* k_asm   = b + off; off += (size_t)NH * S * DQK;
    u16* vt      = b + off; off += (size_t)NH * DH * S;
    u16* attn_bf = b + off; off += (size_t)S * NH * DH;

    rope_table_kernel<<<(S * (DR / 2) + 255) / 256, 256, 0, stream>>>(cosT, sinT);

    convert_bf16_kernel<<<((S * DM / 4) + 255) / 256, 256, 0, stream>>>(x, x_bf, S * DM / 4);

    auto wt = [&](const float* W, u16* dst, int K, int N) {
        wt_convert_kernel<<<dim3(N / 64, K / 64), 256, 0, stream>>>(W, dst, K, N);
    };
    wt(W_kv_down, WT1, DM, DKV);
    wt(W_q_down,  WT1 + (size_t)512 * DM, DM, DQ);
    wt(W_k_rope,  WT1 + (size_t)1536 * DM, DM, NH * DR);
    wt(W_k_up,    WT2, DKV, NH * DH);
    wt(W_v_up,    WT2 + (size_t)2048 * DKV, DKV, NH * DH);
    wt(W_q_up,    WT3, DQ, NH * DH);
    wt(W_q_rope,  WT3 + (size_t)2048 * DQ, DQ, NH * DR);
    wt(W_out,     WT4, DM, DM);

    // G1: x @ [W_kv_down | W_q_down | W_k_rope], N=2560, K=2048
    gemm_bf16_kernel<u16><<<dim3(2560 / 128, S / 64), 256, 0, stream>>>(
        x_bf, WT1, down_kv, down_q, kr_bf, 512, 1536, 512, 1024, 1024, DM);
    // G2: down_kv @ [W_k_up | W_v_up], N=4096, K=512
    gemm_bf16_kernel<u16><<<dim3(4096 / 128, S / 64), 256, 0, stream>>>(
        down_kv, WT2, kc_bf, v_bf, v_bf, 2048, 4096, 2048, 2048, 1, DKV);
    // G3: down_q @ [W_q_up | W_q_rope], N=3072, K=1024
    gemm_bf16_kernel<u16><<<dim3(3072 / 128, S / 64), 256, 0, stream>>>(
        down_q, WT3, qc_bf, qr_bf, qr_bf, 2048, 3072, 2048, 1024, 1, DQ);

    const int total = NH * S * DQK;
    const float scale = 1.0f / sqrtf((float)DQK);
    assemble_qk_bf16_kernel<<<(total + 255) / 256, 256, 0, stream>>>(qc_bf, qr_bf, cosT, sinT, q_asm, scale, total);
    assemble_qk_bf16_kernel<<<(total + 255) / 256, 256, 0, stream>>>(kc_bf, kr_bf, cosT, sinT, k_asm, 1.0f, total);
    v_transpose_bf16_kernel<<<dim3(S / 64, DH / 64, NH), 256, 0, stream>>>(v_bf, vt);

    attn_mfma_kernel<<<NH * (S / 16), 64, 0, stream>>>(q_asm, k_asm, vt, attn_bf);

    // G4: attn_out @ W_out, N=2048, K=2048 -> fp32 d_out
    gemm_bf16_kernel<float><<<dim3(DM / 128, S / 64), 256, 0, stream>>>(
        attn_bf, WT4, out, out, out, DM, DM, DM, DM, DM, DM);
}

// Round 8
// 223.586 us; speedup vs baseline: 1.8790x; 1.8790x over previous
//
#include <hip/hip_runtime.h>
#include <hip/hip_bf16.h>
#include <math.h>

#define S 2048
#define DM 2048
#define NH 16
#define DH 128
#define DR 64
#define DKV 512
#define DQ 1024
#define DQK 192  // DH + DR
#define QSCALE 0.07216878364870323f  // 1/sqrt(192)

typedef __bf16 bf16x8 __attribute__((ext_vector_type(8)));
typedef float f32x4 __attribute__((ext_vector_type(4)));
typedef unsigned short u16;

__device__ inline unsigned int pack2_bf16(float a, float b) {
    __hip_bfloat16 ha = __float2bfloat16(a);
    __hip_bfloat16 hb = __float2bfloat16(b);
    unsigned short ua = *reinterpret_cast<unsigned short*>(&ha);
    unsigned short ub = *reinterpret_cast<unsigned short*>(&hb);
    return (unsigned int)ua | ((unsigned int)ub << 16);
}
__device__ inline u16 f2bf(float v) {
    __hip_bfloat16 hb = __float2bfloat16(v);
    return *reinterpret_cast<u16*>(&hb);
}
__device__ inline void gload_lds16(const void* g, void* l) {
    __builtin_amdgcn_global_load_lds(
        (const __attribute__((address_space(1))) void*)g,
        (__attribute__((address_space(3))) void*)l, 16, 0, 0);
}

// ---------------- RoPE cos/sin table ----------------
__global__ void rope_table_kernel(float* __restrict__ cosT, float* __restrict__ sinT) {
    int idx = blockIdx.x * blockDim.x + threadIdx.x;
    if (idx >= S * (DR / 2)) return;
    int pos = idx / (DR / 2);
    int j   = idx % (DR / 2);
    float inv = __expf(-((float)(2 * j) / (float)DR) * logf(10000.0f));
    float ang = (float)pos * inv;
    cosT[idx] = cosf(ang);
    sinT[idx] = sinf(ang);
}

// ---------------- f32 -> bf16 elementwise (x) ----------------
__global__ void convert_bf16_kernel(const float* __restrict__ in, u16* __restrict__ outp, int n4) {
    int idx = blockIdx.x * blockDim.x + threadIdx.x;
    if (idx >= n4) return;
    float4 v = *reinterpret_cast<const float4*>(&in[(size_t)idx * 4]);
    uint2 w;
    w.x = pack2_bf16(v.x, v.y);
    w.y = pack2_bf16(v.z, v.w);
    *reinterpret_cast<uint2*>(&outp[(size_t)idx * 4]) = w;
}

// ---------------- fused transpose-convert for all 8 weights ----------------
__global__ __launch_bounds__(256) void wt_all_kernel(
    const float* __restrict__ W0, const float* __restrict__ W1, const float* __restrict__ W2,
    const float* __restrict__ W3, const float* __restrict__ W4, const float* __restrict__ W5,
    const float* __restrict__ W6, const float* __restrict__ W7,
    u16* __restrict__ D0, u16* __restrict__ D1, u16* __restrict__ D2, u16* __restrict__ D3,
    u16* __restrict__ D4, u16* __restrict__ D5, u16* __restrict__ D6, u16* __restrict__ D7) {
    __shared__ u16 tile[64][65];
    const float* W; u16* D; int N, K, local;
    int bnum = blockIdx.x;
    if (bnum < 256)       { W = W0; D = D0; N = 512;  K = 2048; local = bnum; }
    else if (bnum < 768)  { W = W1; D = D1; N = 1024; K = 2048; local = bnum - 256; }
    else if (bnum < 1280) { W = W2; D = D2; N = 1024; K = 2048; local = bnum - 768; }
    else if (bnum < 1536) { W = W3; D = D3; N = 2048; K = 512;  local = bnum - 1280; }
    else if (bnum < 1792) { W = W4; D = D4; N = 2048; K = 512;  local = bnum - 1536; }
    else if (bnum < 2304) { W = W5; D = D5; N = 2048; K = 1024; local = bnum - 1792; }
    else if (bnum < 2560) { W = W6; D = D6; N = 1024; K = 1024; local = bnum - 2304; }
    else                  { W = W7; D = D7; N = 2048; K = 2048; local = bnum - 2560; }
    const int nt = N / 64;
    const int n0 = (local % nt) * 64;
    const int k0 = (local / nt) * 64;
    const int tx = threadIdx.x & 15;
    const int ty = threadIdx.x >> 4;
#pragma unroll
    for (int rep = 0; rep < 4; ++rep) {
        int kk = rep * 16 + ty;
        float4 v = *reinterpret_cast<const float4*>(&W[(size_t)(k0 + kk) * N + n0 + tx * 4]);
        tile[kk][tx * 4 + 0] = f2bf(v.x);
        tile[kk][tx * 4 + 1] = f2bf(v.y);
        tile[kk][tx * 4 + 2] = f2bf(v.z);
        tile[kk][tx * 4 + 3] = f2bf(v.w);
    }
    __syncthreads();
#pragma unroll
    for (int rep = 0; rep < 4; ++rep) {
        int nn = rep * 16 + ty;
        uint2 w;
        w.x = (unsigned int)tile[tx * 4 + 0][nn] | ((unsigned int)tile[tx * 4 + 1][nn] << 16);
        w.y = (unsigned int)tile[tx * 4 + 2][nn] | ((unsigned int)tile[tx * 4 + 3][nn] << 16);
        *reinterpret_cast<uint2*>(&D[(size_t)(n0 + nn) * K + k0 + tx * 4]) = w;
    }
}

// ---------------- bf16 MFMA GEMM with fused epilogues ----------------
// 64x128 tile, BK=32, 4 waves (2Mx2N), wave = 32x64 via 2x4 16x16x32 MFMAs.
// Conflict-free LDS slot maps (R6-verified). MODE selects epilogue:
//  0: G1 -> down_kv | down_q | RoPE(k_rope)->k_asm
//  1: G2 -> k_asm content | V transposed -> vt
//  2: G3 -> scale*qc -> q_asm | scale*RoPE(q_rope) -> q_asm
//  3: G4 -> fp32 out
template <int MODE>
__global__ __launch_bounds__(256) void gemm_fused_kernel(
    const u16* __restrict__ A, const u16* __restrict__ BT,
    void* __restrict__ P0v, void* __restrict__ P1v, void* __restrict__ P2v,
    const float* __restrict__ cosT, const float* __restrict__ sinT, int K) {
    __shared__ u16 lds[2][6144];
    const int tid  = threadIdx.x;
    const int wave = tid >> 6;
    const int lane = tid & 63;
    const int c16  = lane & 15;
    const int g    = lane >> 4;
    const int bm = blockIdx.y * 64;
    const int bn = blockIdx.x * 128;
    const int wm = (wave >> 1) * 32;
    const int wn = (wave & 1) * 64;

    f32x4 acc[2][4];
#pragma unroll
    for (int i = 0; i < 2; ++i)
#pragma unroll
        for (int j = 0; j < 4; ++j) acc[i][j] = f32x4{0.f, 0.f, 0.f, 0.f};

    auto stage = [&](int buf, int k0) {
        {
            int L = tid;
            int rp = L >> 3, e = L & 7, x = e ^ (rp & 7);
            int row = 2 * rp + (x >> 2), kc = x & 3;
            gload_lds16(A + (size_t)(bm + row) * K + k0 + kc * 8, &lds[buf][wave * 512]);
        }
#pragma unroll
        for (int r = 0; r < 2; ++r) {
            int L = r * 256 + tid;
            int rp = L >> 3, e = L & 7, x = e ^ (rp & 7);
            int row = 2 * rp + (x >> 2), kc = x & 3;
            gload_lds16(BT + (size_t)(bn + row) * K + k0 + kc * 8,
                        &lds[buf][2048 + (r * 256 + wave * 64) * 8]);
        }
    };

    const int NT = K / 32;
    stage(0, 0);
    __syncthreads();
    int cur = 0;
    for (int t = 0; t < NT; ++t) {
        if (t + 1 < NT) stage(cur ^ 1, (t + 1) * 32);
        bf16x8 af[2], bfr[4];
#pragma unroll
        for (int i = 0; i < 2; ++i) {
            int row  = wm + i * 16 + c16;
            int slot = ((row >> 1) << 3) + ((((row & 1) << 2) + g) ^ ((row >> 1) & 7));
            af[i] = *reinterpret_cast<const bf16x8*>(&lds[cur][slot * 8]);
        }
#pragma unroll
        for (int j = 0; j < 4; ++j) {
            int row  = wn + j * 16 + c16;
            int slot = ((row >> 1) << 3) + ((((row & 1) << 2) + g) ^ ((row >> 1) & 7));
            bfr[j] = *reinterpret_cast<const bf16x8*>(&lds[cur][2048 + slot * 8]);
        }
#pragma unroll
        for (int i = 0; i < 2; ++i)
#pragma unroll
            for (int j = 0; j < 4; ++j)
                acc[i][j] = __builtin_amdgcn_mfma_f32_16x16x32_bf16(af[i], bfr[j], acc[i][j], 0, 0, 0);
        __syncthreads();
        cur ^= 1;
    }

    // ---- fused epilogue (D row = bm+wm+i*16+g*4+r, col = bn+wn+j*16+c16) ----
#pragma unroll
    for (int i = 0; i < 2; ++i)
#pragma unroll
        for (int j = 0; j < 4; ++j) {
            const int mrow = bm + wm + i * 16 + g * 4;
            const int col  = bn + wn + j * 16 + c16;
            if constexpr (MODE == 0) {
                if (col < 512) {
                    u16* down_kv = (u16*)P0v;
#pragma unroll
                    for (int r = 0; r < 4; ++r)
                        down_kv[(size_t)(mrow + r) * DKV + col] = f2bf(acc[i][j][r]);
                } else if (col < 1536) {
                    u16* down_q = (u16*)P1v;
#pragma unroll
                    for (int r = 0; r < 4; ++r)
                        down_q[(size_t)(mrow + r) * DQ + (col - 512)] = f2bf(acc[i][j][r]);
                } else {
                    u16* k_asm = (u16*)P2v;
                    const int cc = col - 1536, h = cc >> 6, rr = cc & 63, jj = rr >> 1;
#pragma unroll
                    for (int r = 0; r < 4; ++r) {
                        int pos = mrow + r;
                        float self = acc[i][j][r];
                        float vp   = __shfl_xor(self, 1);
                        float c = cosT[pos * (DR / 2) + jj];
                        float s = sinT[pos * (DR / 2) + jj];
                        float val = (rr & 1) ? (vp * s + self * c) : (self * c - vp * s);
                        k_asm[((size_t)h * S + pos) * DQK + DH + rr] = f2bf(val);
                    }
                }
            } else if constexpr (MODE == 1) {
                if (col < 2048) {
                    u16* k_asm = (u16*)P0v;
                    const int h = col >> 7, d = col & 127;
#pragma unroll
                    for (int r = 0; r < 4; ++r)
                        k_asm[((size_t)h * S + mrow + r) * DQK + d] = f2bf(acc[i][j][r]);
                } else {
                    u16* vt = (u16*)P1v;
                    const int cc = col - 2048, h = cc >> 7, d = cc & 127;
                    uint2 w;
                    w.x = pack2_bf16(acc[i][j][0], acc[i][j][1]);
                    w.y = pack2_bf16(acc[i][j][2], acc[i][j][3]);
                    *reinterpret_cast<uint2*>(&vt[((size_t)h * DH + d) * S + mrow]) = w;
                }
            } else if constexpr (MODE == 2) {
                u16* q_asm = (u16*)P0v;
                if (col < 2048) {
                    const int h = col >> 7, d = col & 127;
#pragma unroll
                    for (int r = 0; r < 4; ++r)
                        q_asm[((size_t)h * S + mrow + r) * DQK + d] = f2bf(acc[i][j][r] * QSCALE);
                } else {
                    const int cc = col - 2048, h = cc >> 6, rr = cc & 63, jj = rr >> 1;
#pragma unroll
                    for (int r = 0; r < 4; ++r) {
                        int pos = mrow + r;
                        float self = acc[i][j][r];
                        float vp   = __shfl_xor(self, 1);
                        float c = cosT[pos * (DR / 2) + jj];
                        float s = sinT[pos * (DR / 2) + jj];
                        float val = (rr & 1) ? (vp * s + self * c) : (self * c - vp * s);
                        q_asm[((size_t)h * S + pos) * DQK + DH + rr] = f2bf(val * QSCALE);
                    }
                }
            } else {  // MODE 3
                float* outp = (float*)P0v;
#pragma unroll
                for (int r = 0; r < 4; ++r)
                    outp[(size_t)(mrow + r) * DM + col] = acc[i][j][r];
            }
        }
}

// ---------------- MFMA flash attention (R6-verified, 86us) ----------------
// 4 waves/block, QBLK=64, KV tiles of 32 double-buffered via global_load_lds.
// Conflict-free slot maps (consecutive-8-lane phase model), both-sides applied.
__global__ __launch_bounds__(256) void attn_mfma_kernel(const u16* __restrict__ q,   // (NH,S,192) pre-scaled
                                                        const u16* __restrict__ k,   // (NH,S,192)
                                                        const u16* __restrict__ vt,  // (NH,DH,S)
                                                        u16* __restrict__ outp) {    // (S, NH*DH) bf16
    const int wgid = blockIdx.x;
    const int xcd  = wgid & 7;
    const int i    = wgid >> 3;  // 0..63 per xcd
    const int h  = (i < 32) ? (xcd * 2) : (xcd * 2 + 1);
    const int qt = (i < 32) ? (31 - i) : (i - 32);
    const int q0 = qt * 64;

    const int tid  = threadIdx.x;
    const int wave = tid >> 6;
    const int lane = tid & 63;
    const int col  = lane & 15;
    const int g    = lane >> 4;
    const int qw   = q0 + wave * 16;

    __shared__ u16 Kt[2][32 * DQK];              // slot(row,ch)=row*24+8*(ch>>3)+((ch&7)^(row&7))
    __shared__ u16 Vt[2][DH * 32];               // slot(d,kc)=(d>>1)*8+((4*(d&1)+kc)^((d>>1)&7))
    __shared__ __align__(16) u16 p_lds[4][512];  // per-wave P, same slot form as Vt (row=q)

    const int r7  = col & 7;          // K row-class
    const int pv7 = (col >> 1) & 7;   // V/P row-pair class
    const int pvb = (col & 1) << 2;

    // Q fragments: lane holds Q[qw+col][g*8+e + 32c]
    bf16x8 qf[6];
    const u16* qbase = q + ((size_t)h * S + qw + col) * DQK + g * 8;
#pragma unroll
    for (int c = 0; c < 6; ++c) qf[c] = *reinterpret_cast<const bf16x8*>(qbase + c * 32);

    f32x4 acc[8];
#pragma unroll
    for (int c = 0; c < 8; ++c) acc[c] = f32x4{0.f, 0.f, 0.f, 0.f};
    float m_run = -1e30f, l_run = 0.f;

    auto stage = [&](int buf, int j0) {
        // K: 768 chunks; inverse: row=L/24, rem=L%24, ch=8*(rem>>3)+((rem&7)^(row&7))
#pragma unroll
        for (int r = 0; r < 3; ++r) {
            int L   = r * 256 + tid;
            int row = L / 24, rem = L - row * 24;
            int ch  = ((rem >> 3) << 3) + ((rem & 7) ^ (row & 7));
            gload_lds16(k + ((size_t)h * S + j0 + row) * DQK + ch * 8,
                        &Kt[buf][(r * 256 + wave * 64) * 8]);
        }
        // V: 512 chunks; inverse: rp=L>>3, x=(L&7)^(rp&7), d=2rp+(x>>2), kc=x&3
#pragma unroll
        for (int r = 0; r < 2; ++r) {
            int L  = r * 256 + tid;
            int rp = L >> 3, x = (L & 7) ^ (rp & 7);
            int d  = 2 * rp + (x >> 2), kc = x & 3;
            gload_lds16(vt + ((size_t)h * DH + d) * S + j0 + kc * 8,
                        &Vt[buf][(r * 256 + wave * 64) * 8]);
        }
    };

    const int kend = q0 + 64;
    stage(0, 0);
    __syncthreads();
    int cur = 0;
    for (int j0 = 0; j0 < kend; j0 += 32) {
        if (j0 + 32 < kend) stage(cur ^ 1, j0 + 32);
        // ---- QK^T from Kt[cur]
        f32x4 st[2];
        st[0] = f32x4{0.f, 0.f, 0.f, 0.f};
        st[1] = f32x4{0.f, 0.f, 0.f, 0.f};
#pragma unroll
        for (int t = 0; t < 2; ++t) {
            int rb = (16 * t + col) * 24;
#pragma unroll
            for (int c = 0; c < 6; ++c) {
                int ch   = g + 4 * c;
                int slot = rb + ((ch >> 3) << 3) + ((ch & 7) ^ r7);
                bf16x8 kf = *reinterpret_cast<const bf16x8*>(&Kt[cur][slot * 8]);
                st[t] = __builtin_amdgcn_mfma_f32_16x16x32_bf16(kf, qf[c], st[t], 0, 0, 0);
            }
        }
        // ---- causal mask (q = qw+col, key = j0+16t+4g+r)
#pragma unroll
        for (int t = 0; t < 2; ++t) {
            if (j0 + 16 * t + 15 > qw) {
#pragma unroll
                for (int r = 0; r < 4; ++r) {
                    int key = j0 + 16 * t + 4 * g + r;
                    st[t][r] = (key > qw + col) ? -1e30f : st[t][r];
                }
            }
        }
        // ---- online softmax with defer-max
        float tmax = fmaxf(fmaxf(fmaxf(st[0][0], st[0][1]), fmaxf(st[0][2], st[0][3])),
                           fmaxf(fmaxf(st[1][0], st[1][1]), fmaxf(st[1][2], st[1][3])));
        tmax = fmaxf(tmax, __shfl_xor(tmax, 16));
        tmax = fmaxf(tmax, __shfl_xor(tmax, 32));
        float m_new;
        if (__all(tmax - m_run <= 8.0f)) {
            m_new = m_run;  // defer: P bounded by e^8, no rescale
        } else {
            m_new = fmaxf(m_run, tmax);
            float r_scale = __expf(m_run - m_new);
            l_run *= r_scale;
#pragma unroll
            for (int c = 0; c < 8; ++c) {
                acc[c][0] *= r_scale; acc[c][1] *= r_scale;
                acc[c][2] *= r_scale; acc[c][3] *= r_scale;
            }
            m_run = m_new;
        }
        float p[8];
        float psum = 0.f;
#pragma unroll
        for (int t = 0; t < 2; ++t)
#pragma unroll
            for (int r = 0; r < 4; ++r) {
                float pv = __expf(st[t][r] - m_new);
                p[t * 4 + r] = pv;
                psum += pv;
            }
        psum += __shfl_xor(psum, 16);
        psum += __shfl_xor(psum, 32);
        l_run += psum;
        // ---- P -> p_lds (wave-private; chunk = 2t+(g>>1), half = g&1)
#pragma unroll
        for (int t = 0; t < 2; ++t) {
            uint2 w;
            w.x = pack2_bf16(p[t * 4 + 0], p[t * 4 + 1]);
            w.y = pack2_bf16(p[t * 4 + 2], p[t * 4 + 3]);
            int ch   = 2 * t + (g >> 1);
            int slot = ((col >> 1) << 3) + ((pvb + ch) ^ pv7);
            *reinterpret_cast<uint2*>(&p_lds[wave][slot * 8 + (g & 1) * 4]) = w;
        }
        {
            int slot = ((col >> 1) << 3) + ((pvb + g) ^ pv7);
            bf16x8 pf = *reinterpret_cast<const bf16x8*>(&p_lds[wave][slot * 8]);
            // ---- PV from Vt[cur]
#pragma unroll
            for (int c = 0; c < 8; ++c) {
                int d  = 16 * c + col;
                int vs = ((d >> 1) << 3) + ((pvb + g) ^ pv7);
                bf16x8 vf = *reinterpret_cast<const bf16x8*>(&Vt[cur][vs * 8]);
                acc[c] = __builtin_amdgcn_mfma_f32_16x16x32_bf16(vf, pf, acc[c], 0, 0, 0);
            }
        }
        __syncthreads();  // all reads of cur done + staged cur^1 drained
        cur ^= 1;
    }

    float inv_l = 1.0f / l_run;
#pragma unroll
    for (int c = 0; c < 8; ++c)
#pragma unroll
        for (int r = 0; r < 4; ++r)
            outp[(size_t)(qw + col) * (NH * DH) + h * DH + 16 * c + 4 * g + r] = f2bf(acc[c][r] * inv_l);
}

// ---------------- launch ----------------
extern "C" void kernel_launch(void* const* d_in, const int* in_sizes, int n_in,
                              void* d_out, int out_size, void* d_ws, size_t ws_size,
                              hipStream_t stream) {
    const float* x         = (const float*)d_in[0];
    const float* W_kv_down = (const float*)d_in[2];
    const float* W_k_up    = (const float*)d_in[3];
    const float* W_v_up    = (const float*)d_in[4];
    const float* W_q_down  = (const float*)d_in[5];
    const float* W_q_up    = (const float*)d_in[6];
    const float* W_q_rope  = (const float*)d_in[7];
    const float* W_k_rope  = (const float*)d_in[8];
    const float* W_out     = (const float*)d_in[9];
    float* out = (float*)d_out;

    float* w = (float*)d_ws;
    float* cosT = w;
    float* sinT = w + (size_t)S * (DR / 2);
    u16* b = (u16*)(w + 2 * (size_t)S * (DR / 2));
    size_t off = 0;
    u16* x_bf    = b + off; off += (size_t)S * DM;
    u16* WT1     = b + off; off += (size_t)2560 * DM;    // [W_kv_down^T 512][W_q_down^T 1024][W_k_rope^T 1024], K=2048
    u16* WT2     = b + off; off += (size_t)4096 * DKV;   // [W_k_up^T 2048][W_v_up^T 2048], K=512
    u16* WT3     = b + off; off += (size_t)3072 * DQ;    // [W_q_up^T 2048][W_q_rope^T 1024], K=1024
    u16* WT4     = b + off; off += (size_t)DM * DM;      // W_out^T, K=2048
    u16* down_kv = b + off; off += (size_t)S * DKV;
    u16* down_q  = b + off; off += (size_t)S * DQ;
    u16* q_asm   = b + off; off += (size_t)NH * S * DQK;
    u16* k_asm   = b + off; off += (size_t)NH * S * DQK;
    u16* vt      = b + off; off += (size_t)NH * DH * S;
    u16* attn_bf = b + off; off += (size_t)S * NH * DH;

    rope_table_kernel<<<(S * (DR / 2) + 255) / 256, 256, 0, stream>>>(cosT, sinT);

    convert_bf16_kernel<<<((S * DM / 4) + 255) / 256, 256, 0, stream>>>(x, x_bf, S * DM / 4);

    wt_all_kernel<<<3584, 256, 0, stream>>>(
        W_kv_down, W_q_down, W_k_rope, W_k_up, W_v_up, W_q_up, W_q_rope, W_out,
        WT1, WT1 + (size_t)512 * DM, WT1 + (size_t)1536 * DM,
        WT2, WT2 + (size_t)2048 * DKV,
        WT3, WT3 + (size_t)2048 * DQ, WT4);

    // G1: x @ [W_kv_down | W_q_down | W_k_rope], N=2560, K=2048 -> down_kv, down_q, RoPE(k_r)->k_asm
    gemm_fused_kernel<0><<<dim3(2560 / 128, S / 64), 256, 0, stream>>>(
        x_bf, WT1, down_kv, down_q, k_asm, cosT, sinT, DM);
    // G2: down_kv @ [W_k_up | W_v_up], N=4096, K=512 -> k_asm content, V^T->vt
    gemm_fused_kernel<1><<<dim3(4096 / 128, S / 64), 256, 0, stream>>>(
        down_kv, WT2, k_asm, vt, nullptr, cosT, sinT, DKV);
    // G3: down_q @ [W_q_up | W_q_rope], N=3072, K=1024 -> scaled q (+RoPE) -> q_asm
    gemm_fused_kernel<2><<<dim3(3072 / 128, S / 64), 256, 0, stream>>>(
        down_q, WT3, q_asm, nullptr, nullptr, cosT, sinT, DQ);

    attn_mfma_kernel<<<512, 256, 0, stream>>>(q_asm, k_asm, vt, attn_bf);

    // G4: attn_out @ W_out, N=2048, K=2048 -> fp32 d_out
    gemm_fused_kernel<3><<<dim3(DM / 128, S / 64), 256, 0, stream>>>(
        attn_bf, WT4, out, nullptr, nullptr, cosT, sinT, DM);
}